// Round 3
// baseline (19156.520 us; speedup 1.0000x reference)
//
#include <hip/hip_runtime.h>
#include <math.h>

#define NN 20000
#define NE 320000

typedef const float* fp;

__device__ __forceinline__ float siluf(float v) { return v / (1.f + expf(-v)); }

// dot: fp32 weight row * fp32 LDS vector
__device__ __forceinline__ float dotrow(fp w, const float* __restrict__ in, int n) {
    float acc = 0.f;
#pragma unroll 8
    for (int i = 0; i < n; i++) acc += w[i] * in[i];
    return acc;
}

// tree reduction over 128 threads; safe for immediate buffer reuse
__device__ __forceinline__ float block_reduce(float v, float* buf, int tid) {
    buf[tid] = v;
    __syncthreads();
#pragma unroll
    for (int off = 64; off > 0; off >>= 1) {
        if (tid < off) buf[tid] += buf[tid + off];
        __syncthreads();
    }
    float r = buf[0];
    __syncthreads();
    return r;
}

// per-node: active-channel count and masked pooled coordinate
__global__ void k_node_pre(fp x, fp cw, float* __restrict__ csum, float* __restrict__ pool) {
    int n = blockIdx.x * blockDim.x + threadIdx.x;
    if (n >= NN) return;
    float cnt = 0.f, px = 0.f, py = 0.f, pz = 0.f;
#pragma unroll
    for (int c = 0; c < 14; c++) {
        float w = cw[n * 14 + c];
        if (w != 0.f) {
            cnt += 1.f;
            px += x[(n * 14 + c) * 3 + 0];
            py += x[(n * 14 + c) * 3 + 1];
            pz += x[(n * 14 + c) * 3 + 2];
        }
    }
    if (cnt < 1.f) cnt = 1.f;
    csum[n] = cnt;
    pool[n * 3 + 0] = px / cnt;
    pool[n * 3 + 1] = py / cnt;
    pool[n * 3 + 2] = pz / cnt;
}

__global__ __launch_bounds__(128) void k_edge(
    fp h, fp x, const int* __restrict__ row, const int* __restrict__ col,
    fp attr, fp cw,
    fp rW, fp rB, fp e1W, fp e1B, fp e2W, fp e2B, fp aW, fp aB,
    fp c1W, fp c1B, fp c2W, fp c2B,
    const float* __restrict__ csum, const float* __restrict__ pooled,
    float* __restrict__ xacc, float* __restrict__ aggacc,
    float* __restrict__ cntr, float* __restrict__ cntc) {
    __shared__ float s_xr[42], s_xc[42], s_cwr[14], s_cwc[14];
    __shared__ float s_ar[224], s_ac[224];
    __shared__ float s_msg[196], s_tmp[224], s_rad[256];
    __shared__ float s_ef[384];
    __shared__ float s_v1[128], s_v2[128], s_v3[128], s_c1[128];
    __shared__ float s_red[128];
    __shared__ float s_ch[14], s_pool[14];

    const int e = blockIdx.x;
    const int tid = threadIdx.x;
    int r = row[e];  if ((unsigned)r  >= NN) r  = 0;   // defensive clamp
    int cl = col[e]; if ((unsigned)cl >= NN) cl = 0;

    // ---- stage 1: gathers ----
    for (int p = tid; p < 84; p += 128) {
        if (p < 42) s_xr[p] = x[r * 42 + p];
        else        s_xc[p - 42] = x[cl * 42 + (p - 42)];
    }
    if (tid < 28) {
        if (tid < 14) s_cwr[tid] = cw[r * 14 + tid];
        else          s_cwc[tid - 14] = cw[cl * 14 + (tid - 14)];
    }
    for (int p = tid; p < 448; p += 128) {
        if (p < 224) s_ar[p] = attr[r * 224 + p];
        else         s_ac[p - 224] = attr[cl * 224 + (p - 224)];
    }
    s_ef[tid] = h[r * 128 + tid];
    s_ef[128 + tid] = h[cl * 128 + tid];
    __syncthreads();

    // ---- stage 2: weighted pairwise channel distances ----
    for (int p = tid; p < 196; p += 128) {
        int i = p / 14, j = p - i * 14;
        float dx = s_xr[i * 3 + 0] - s_xc[j * 3 + 0];
        float dy = s_xr[i * 3 + 1] - s_xc[j * 3 + 1];
        float dz = s_xr[i * 3 + 2] - s_xc[j * 3 + 2];
        s_msg[p] = sqrtf(dx * dx + dy * dy + dz * dz) * s_cwr[i] * s_cwc[j];
    }
    __syncthreads();

    // ---- stage 3: tmp[a][j] = sum_i attr_r[i][a] * msg[i][j] ----
    for (int p = tid; p < 224; p += 128) {
        int a = p / 14, j = p - a * 14;
        float acc = 0.f;
#pragma unroll
        for (int i = 0; i < 14; i++) acc += s_ar[i * 16 + a] * s_msg[i * 14 + j];
        s_tmp[p] = acc;
    }
    __syncthreads();

    // ---- stage 4: radial[a][b] = sum_j tmp[a][j]*attr_c[j][b] ----
    float ss = 0.f;
    for (int p = tid; p < 256; p += 128) {
        int a = p >> 4, b = p & 15;
        float acc = 0.f;
#pragma unroll
        for (int j = 0; j < 14; j++) acc += s_tmp[a * 14 + j] * s_ac[j * 16 + b];
        s_rad[p] = acc;
        ss += acc * acc;
    }
    __syncthreads();
    float totss = block_reduce(ss, s_red, tid);
    float rnorm = sqrtf(totss) + 1.0f;

    // ---- stage 5: radial MLP ----
    s_ef[256 + tid] = (dotrow(rW + tid * 256, s_rad, 256) + rB[tid]) / rnorm;
    __syncthreads();

    // ---- stage 6: e1 ----
    s_v1[tid] = siluf(dotrow(e1W + tid * 384, s_ef, 384) + e1B[tid]);
    __syncthreads();

    // ---- stage 7: e2 ----
    s_v2[tid] = siluf(dotrow(e2W + tid * 128, s_v1, 128) + e2B[tid]);
    __syncthreads();

    // ---- stage 8: attention gate ----
    float attsum = block_reduce(aW[tid] * s_v2[tid], s_red, tid);
    float gate = 1.f / (1.f + expf(-(attsum + aB[0])));
    s_v3[tid] = s_v2[tid] * gate;   // final edge feature ef
    __syncthreads();

    // ---- stage 9: c1 ----
    s_c1[tid] = siluf(dotrow(c1W + tid * 128, s_v3, 128) + c1B[tid]);
    __syncthreads();

    // ---- stage 10: c2 (14 outputs) ----
    if (tid < 14) s_ch[tid] = dotrow(c2W + tid * 128, s_c1, 128) + c2B[tid];
    __syncthreads();

    // ---- stage 11: roller pooling (closed-form sliding window) ----
    if (tid < 14) {
        int t = (int)(csum[r] + 0.5f) - 1;      // tsize in [0,13]
        if (t < 0) t = 0; if (t > 13) t = 13;
        int Wd = 14 - t;
        int jend = tid + Wd - 1; if (jend > 13) jend = 13;
        float acc = 0.f;
        for (int j = tid; j <= jend; j++) acc += s_ch[j];
        s_pool[tid] = acc / (float)Wd;
    }
    __syncthreads();

    // ---- stage 12: scatters ----
    if (tid < 42) {
        int i = tid / 3, d = tid - i * 3;
        float diff = s_xr[tid] - pooled[cl * 3 + d];
        atomicAdd(&xacc[r * 42 + tid], diff * s_pool[i]);
    }
    atomicAdd(&aggacc[cl * 128 + tid], s_v3[tid]);
    if (tid == 0) {
        atomicAdd(&cntr[r], 1.f);
        atomicAdd(&cntc[cl], 1.f);
    }
}

__global__ __launch_bounds__(128) void k_node_post(
    fp h, fp x, fp n1W, fp n1B, fp n2W, fp n2B, fp lng, fp lnb,
    const float* __restrict__ agg, const float* __restrict__ cntc,
    const float* __restrict__ xacc, const float* __restrict__ cntr,
    float* __restrict__ outh, float* __restrict__ outx) {
    __shared__ float s_in[256], s_mid[128], s_red[128];
    const int n = blockIdx.x, tid = threadIdx.x;
    float cc = cntc[n]; if (cc < 1.f) cc = 1.f;
    s_in[tid] = h[n * 128 + tid];
    s_in[128 + tid] = agg[n * 128 + tid] / cc;
    __syncthreads();
    s_mid[tid] = siluf(dotrow(n1W + tid * 256, s_in, 256) + n1B[tid]);
    __syncthreads();
    float y = s_in[tid] + dotrow(n2W + tid * 128, s_mid, 128) + n2B[tid];
    float mu = block_reduce(y, s_red, tid) * (1.f / 128.f);
    float d = y - mu;
    float var = block_reduce(d * d, s_red, tid) * (1.f / 128.f);
    float ho = d * rsqrtf(var + 1e-5f) * lng[tid] + lnb[tid];
    outh[n * 128 + tid] = ho;
    if (tid < 42) {
        float cr = cntr[n]; if (cr < 1.f) cr = 1.f;
        outx[n * 42 + tid] = x[n * 42 + tid] + xacc[n * 42 + tid] / cr;
    }
}

extern "C" void kernel_launch(void* const* d_in, const int* in_sizes, int n_in,
                              void* d_out, int out_size, void* d_ws, size_t ws_size,
                              hipStream_t stream) {
    fp h   = (fp)d_in[0];
    fp x   = (fp)d_in[1];
    const int* row = (const int*)d_in[2];
    const int* col = (const int*)d_in[3];
    fp attr= (fp)d_in[4];
    fp cw  = (fp)d_in[5];
    fp rW  = (fp)d_in[6];  fp rB  = (fp)d_in[7];
    fp e1W = (fp)d_in[8];  fp e1B = (fp)d_in[9];
    fp e2W = (fp)d_in[10]; fp e2B = (fp)d_in[11];
    fp aW  = (fp)d_in[12]; fp aB  = (fp)d_in[13];
    fp c1W = (fp)d_in[14]; fp c1B = (fp)d_in[15];
    fp c2W = (fp)d_in[16]; fp c2B = (fp)d_in[17];
    fp n1W = (fp)d_in[18]; fp n1B = (fp)d_in[19];
    fp n2W = (fp)d_in[20]; fp n2B = (fp)d_in[21];
    fp lng = (fp)d_in[22]; fp lnb = (fp)d_in[23];

    // fp32 workspace layout:
    // xacc [0, 840000)  agg [840000, 3400000)  cntr [3.40M, 3.42M)
    // cntc [3.42M, 3.44M)  csum [3.44M, 3.46M)  pool [3.46M, 3.52M)
    float* ws   = (float*)d_ws;
    float* xacc = ws;
    float* agg  = ws + 840000;
    float* cntr = ws + 3400000;
    float* cntc = ws + 3420000;
    float* csum = ws + 3440000;
    float* pool = ws + 3460000;

    hipMemsetAsync(d_ws, 0, 3520000 * sizeof(float), stream);

    k_node_pre<<<(NN + 255) / 256, 256, 0, stream>>>(x, cw, csum, pool);

    k_edge<<<NE, 128, 0, stream>>>(h, x, row, col, attr, cw,
                                   rW, rB, e1W, e1B, e2W, e2B, aW, aB,
                                   c1W, c1B, c2W, c2B,
                                   csum, pool, xacc, agg, cntr, cntc);

    float* outh = (float*)d_out;
    float* outx = outh + NN * 128;
    k_node_post<<<NN, 128, 0, stream>>>(h, x, n1W, n1B, n2W, n2B, lng, lnb,
                                        agg, cntc, xacc, cntr, outh, outx);
}

// Round 4
// 1568.100 us; speedup vs baseline: 12.2164x; 12.2164x over previous
//
#include <hip/hip_runtime.h>
#include <math.h>

#define NN 20000
#define NE 320000

typedef const float* fp;
typedef short short8 __attribute__((ext_vector_type(8)));
typedef float f32x4 __attribute__((ext_vector_type(4)));

__device__ __forceinline__ short F2B(float f) {
    unsigned u = __float_as_uint(f);
    unsigned r = (u + 0x7fffu + ((u >> 16) & 1u)) >> 16;
    return (short)r;
}
__device__ __forceinline__ float B2F(short s) {
    return __uint_as_float(((unsigned)(unsigned short)s) << 16);
}
__device__ __forceinline__ float siluf(float v) { return v / (1.f + __expf(-v)); }

// ---------------- weight fp32->bf16 conversion (run every launch) -------------
// layout in bf16 region (element offsets):
// rW 0..32768 | e1W ..81920 | e2W ..98304 | c1W ..114688 | c2W(16x128 pad) ..116736
// n1W ..149504 | n2W ..165888
__global__ void k_prep_w(fp rW, fp e1W, fp e2W, fp c1W, fp c2W, fp n1W, fp n2W,
                         short* __restrict__ wb) {
    int i = blockIdx.x * 256 + threadIdx.x;
    if (i >= 165888) return;
    float v;
    if      (i < 32768)  v = rW[i];
    else if (i < 81920)  v = e1W[i - 32768];
    else if (i < 98304)  v = e2W[i - 81920];
    else if (i < 114688) v = c1W[i - 98304];
    else if (i < 116736) { int q = i - 114688; v = (q < 1792) ? c2W[q] : 0.f; }
    else if (i < 149504) v = n1W[i - 116736];
    else                 v = n2W[i - 149504];
    wb[i] = F2B(v);
}

// ---------------- per-node precompute: csum + masked pooled coord -------------
__global__ void k_node_pre(fp x, fp cw, float* __restrict__ csum, float* __restrict__ pool) {
    int n = blockIdx.x * blockDim.x + threadIdx.x;
    if (n >= NN) return;
    float cnt = 0.f, px = 0.f, py = 0.f, pz = 0.f;
#pragma unroll
    for (int c = 0; c < 14; c++) {
        float w = cw[n * 14 + c];
        if (w != 0.f) {
            cnt += 1.f;
            px += x[(n * 14 + c) * 3 + 0];
            py += x[(n * 14 + c) * 3 + 1];
            pz += x[(n * 14 + c) * 3 + 2];
        }
    }
    if (cnt < 1.f) cnt = 1.f;
    csum[n] = cnt;
    pool[n * 3 + 0] = px / cnt;
    pool[n * 3 + 1] = py / cnt;
    pool[n * 3 + 2] = pz / cnt;
}

// wave-cooperative GEMM tiles: O[m][n] += A[32xK] @ W[NOxK]^T  (bf16 in, fp32 acc)
// wave handles M-tile mt (rows mt*16..+15) and N-tiles nt0..nt0+nts-1
__device__ __forceinline__ void gemm_tiles(const short* __restrict__ A, int sA,
                                           const short* __restrict__ W, int K,
                                           int mt, int nt0, int nts, f32x4* acc) {
    const int lane = threadIdx.x & 63;
    const int mrow = mt * 16 + (lane & 15);
    const int kq = (lane >> 4) * 8;
    for (int t = 0; t < nts; t++) acc[t] = (f32x4){0.f, 0.f, 0.f, 0.f};
    for (int k0 = 0; k0 < K; k0 += 32) {
        short8 a = *(const short8*)(A + mrow * sA + k0 + kq);
#pragma unroll
        for (int t = 0; t < nts; t++) {
            short8 b = *(const short8*)(W + ((nt0 + t) * 16 + (lane & 15)) * K + k0 + kq);
            acc[t] = __builtin_amdgcn_mfma_f32_16x16x32_bf16(a, b, acc[t], 0, 0, 0);
        }
    }
}

// ---------------- fused edge kernel: 32 edges / block, 256 threads ------------
__global__ __launch_bounds__(256, 2) void k_edge(
    fp h, fp x, const int* __restrict__ row, const int* __restrict__ col,
    fp attr, fp cw, const short* __restrict__ wb,
    fp rB, fp e1B, fp e2B, fp aW, fp aB, fp c1B, fp c2B,
    const float* __restrict__ csum, const float* __restrict__ pooledc,
    float* __restrict__ xacc, float* __restrict__ agg,
    float* __restrict__ cntr, float* __restrict__ cntc) {
    __shared__ int   s_r[32], s_c[32];
    __shared__ float s_xr[32][42];
    __shared__ float s_rnorm[32], s_gate[32];
    __shared__ float s_red8[32][8];
    __shared__ float s_ch[32][14], s_pool[32][14];
    __shared__ __attribute__((aligned(16))) short s_A[32 * 392];     // [hr|hc|rad_out] bf16
    __shared__ __attribute__((aligned(16))) short s_radv2[32 * 264]; // rad raw / later v2
    __shared__ __attribute__((aligned(16))) char  s_un[22848];       // prep transient / v1+c1o

    const int tid = threadIdx.x;
    const int wave = tid >> 6;
    const int mt = wave & 1, nh = wave >> 1;
    const int e0 = blockIdx.x * 32;

    short* rad = s_radv2;
    short* v2  = s_radv2;
    short* v1  = (short*)s_un;             // [32*136]
    short* c1o = (short*)s_un + 32 * 136;  // [32*136]
    // prep-phase transient aliases (dead before v1/c1o are written)
    short* arT  = (short*)s_un;            // [8*224] bf16
    short* acT  = arT + 8 * 224;           // [8*224] bf16
    float* xcT  = (float*)(acT + 8 * 224); // [8*42]
    float* cwrT = xcT + 8 * 42;            // [8*14]
    float* cwcT = cwrT + 8 * 14;           // [8*14]
    float* msgT = cwcT + 8 * 14;           // [8*196]
    float* tmpT = msgT + 8 * 196;          // [8*224]

    const short* rWb  = wb;
    const short* e1Wb = wb + 32768;
    const short* e2Wb = wb + 81920;
    const short* c1Wb = wb + 98304;
    const short* c2Wb = wb + 114688;

    if (tid < 32) { s_r[tid] = row[e0 + tid]; s_c[tid] = col[e0 + tid]; }
    __syncthreads();

    // gather h_r, h_c (bf16 into s_A) and x_r (fp32)
    for (int p = tid; p < 32 * 128; p += 256) {
        int e = p >> 7, f = p & 127;
        s_A[e * 392 + f]       = F2B(h[s_r[e] * 128 + f]);
        s_A[e * 392 + 128 + f] = F2B(h[s_c[e] * 128 + f]);
    }
    for (int p = tid; p < 32 * 42; p += 256) {
        int e = p / 42, q = p - e * 42;
        s_xr[e][q] = x[s_r[e] * 42 + q];
    }

    // ---- radial prep in 4 half-batches of 8 edges ----
    for (int b = 0; b < 4; b++) {
        __syncthreads();  // protect transient from previous iteration readers
        for (int p = tid; p < 8 * 224; p += 256) {
            int le = p / 224, i = p - le * 224;
            arT[p] = F2B(attr[s_r[b * 8 + le] * 224 + i]);
            acT[p] = F2B(attr[s_c[b * 8 + le] * 224 + i]);
        }
        for (int p = tid; p < 8 * 42; p += 256) {
            int le = p / 42, i = p - le * 42;
            xcT[p] = x[s_c[b * 8 + le] * 42 + i];
        }
        if (tid < 112)      { int le = tid / 14, i = tid - le * 14; cwrT[tid] = cw[s_r[b * 8 + le] * 14 + i]; }
        else if (tid < 224) { int q = tid - 112; int le = q / 14, i = q - le * 14; cwcT[q] = cw[s_c[b * 8 + le] * 14 + i]; }
        __syncthreads();
        for (int p = tid; p < 8 * 196; p += 256) {
            int le = p / 196, ij = p - le * 196, i = ij / 14, j = ij - i * 14;
            int eg = b * 8 + le;
            float dx = s_xr[eg][i * 3 + 0] - xcT[le * 42 + j * 3 + 0];
            float dy = s_xr[eg][i * 3 + 1] - xcT[le * 42 + j * 3 + 1];
            float dz = s_xr[eg][i * 3 + 2] - xcT[le * 42 + j * 3 + 2];
            msgT[p] = sqrtf(dx * dx + dy * dy + dz * dz) * cwrT[le * 14 + i] * cwcT[le * 14 + j];
        }
        __syncthreads();
        for (int p = tid; p < 8 * 224; p += 256) {
            int le = p / 224, aj = p - le * 224, a = aj / 14, j = aj - a * 14;
            float acc = 0.f;
#pragma unroll
            for (int i = 0; i < 14; i++) acc += B2F(arT[le * 224 + i * 16 + a]) * msgT[le * 196 + i * 14 + j];
            tmpT[le * 224 + a * 14 + j] = acc;
        }
        __syncthreads();
        for (int p = tid; p < 8 * 256; p += 256) {
            int le = p >> 8, ab = p & 255, a = ab >> 4, bb = ab & 15;
            float acc = 0.f;
#pragma unroll
            for (int j = 0; j < 14; j++) acc += tmpT[le * 224 + a * 14 + j] * B2F(acT[le * 224 + j * 16 + bb]);
            rad[(b * 8 + le) * 264 + ab] = F2B(acc);
        }
    }
    __syncthreads();

    // ---- rnorm per edge ----
    {
        int e = tid >> 3, j = tid & 7;
        float ss = 0.f;
        for (int q = j * 32; q < j * 32 + 32; q++) { float v = B2F(rad[e * 264 + q]); ss += v * v; }
        s_red8[e][j] = ss;
    }
    __syncthreads();
    if (tid < 32) {
        float ss = 0.f;
#pragma unroll
        for (int j = 0; j < 8; j++) ss += s_red8[tid][j];
        s_rnorm[tid] = sqrtf(ss) + 1.0f;
    }
    __syncthreads();

    f32x4 acc[4];
    const int lane = tid & 63;
    // ---- radial MLP: [32x256]@rW^T -> s_A[:,256:384] ----
    gemm_tiles(rad, 264, rWb, 256, mt, nh * 4, 4, acc);
#pragma unroll
    for (int t = 0; t < 4; t++)
#pragma unroll
        for (int i = 0; i < 4; i++) {
            int m = mt * 16 + (lane >> 4) * 4 + i, n = (nh * 4 + t) * 16 + (lane & 15);
            s_A[m * 392 + 256 + n] = F2B((acc[t][i] + rB[n]) / s_rnorm[m]);
        }
    __syncthreads();

    // ---- e1: [32x384]@e1W^T, silu -> v1 ----
    gemm_tiles(s_A, 392, e1Wb, 384, mt, nh * 4, 4, acc);
#pragma unroll
    for (int t = 0; t < 4; t++)
#pragma unroll
        for (int i = 0; i < 4; i++) {
            int m = mt * 16 + (lane >> 4) * 4 + i, n = (nh * 4 + t) * 16 + (lane & 15);
            v1[m * 136 + n] = F2B(siluf(acc[t][i] + e1B[n]));
        }
    __syncthreads();

    // ---- e2: silu -> v2 (overwrites rad; rad dead) ----
    gemm_tiles(v1, 136, e2Wb, 128, mt, nh * 4, 4, acc);
    __syncthreads();  // ensure all rad reads done before overwrite
#pragma unroll
    for (int t = 0; t < 4; t++)
#pragma unroll
        for (int i = 0; i < 4; i++) {
            int m = mt * 16 + (lane >> 4) * 4 + i, n = (nh * 4 + t) * 16 + (lane & 15);
            v2[m * 136 + n] = F2B(siluf(acc[t][i] + e2B[n]));
        }
    __syncthreads();

    // ---- attention gate ----
    {
        int e = tid >> 3, j = tid & 7;
        float s = 0.f;
        for (int f = j * 16; f < j * 16 + 16; f++) s += B2F(v2[e * 136 + f]) * aW[f];
        s_red8[e][j] = s;
    }
    __syncthreads();
    if (tid < 32) {
        float s = 0.f;
#pragma unroll
        for (int j = 0; j < 8; j++) s += s_red8[tid][j];
        s_gate[tid] = 1.f / (1.f + __expf(-(s + aB[0])));
    }
    __syncthreads();
    for (int p = tid; p < 32 * 128; p += 256) {
        int e = p >> 7, f = p & 127;
        v1[e * 136 + f] = F2B(B2F(v2[e * 136 + f]) * s_gate[e]);  // v3 -> v1 (e1out dead)
    }
    __syncthreads();

    // ---- c1: silu -> c1o ----
    gemm_tiles(v1, 136, c1Wb, 128, mt, nh * 4, 4, acc);
#pragma unroll
    for (int t = 0; t < 4; t++)
#pragma unroll
        for (int i = 0; i < 4; i++) {
            int m = mt * 16 + (lane >> 4) * 4 + i, n = (nh * 4 + t) * 16 + (lane & 15);
            c1o[m * 136 + n] = F2B(siluf(acc[t][i] + c1B[n]));
        }
    __syncthreads();

    // ---- c2: [32x128]@c2W^T (16-padded) -> s_ch ----
    if (nh == 0) {
        gemm_tiles(c1o, 136, c2Wb, 128, mt, 0, 1, acc);
#pragma unroll
        for (int i = 0; i < 4; i++) {
            int m = mt * 16 + (lane >> 4) * 4 + i, n = lane & 15;
            if (n < 14) s_ch[m][n] = acc[0][i] + c2B[n];
        }
    }
    __syncthreads();

    // ---- roller pooling (closed-form sliding window) ----
    if (tid < 32) {
        int t = (int)(csum[s_r[tid]] + 0.5f) - 1;
        if (t < 0) t = 0; if (t > 13) t = 13;
        int Wd = 14 - t;
        for (int i = 0; i < 14; i++) {
            int jend = i + Wd - 1; if (jend > 13) jend = 13;
            float a = 0.f;
            for (int j = i; j <= jend; j++) a += s_ch[tid][j];
            s_pool[tid][i] = a / (float)Wd;
        }
    }
    __syncthreads();

    // ---- scatters ----
    for (int p = tid; p < 32 * 42; p += 256) {
        int e = p / 42, q = p - e * 42, i = q / 3, d = q - i * 3;
        float diff = s_xr[e][q] - pooledc[s_c[e] * 3 + d];
        atomicAdd(&xacc[s_r[e] * 42 + q], diff * s_pool[e][i]);
    }
    for (int p = tid; p < 32 * 128; p += 256) {
        int e = p >> 7, f = p & 127;
        atomicAdd(&agg[s_c[e] * 128 + f], B2F(v1[e * 136 + f]));
    }
    if (tid < 32) {
        atomicAdd(&cntr[s_r[tid]], 1.f);
        atomicAdd(&cntc[s_c[tid]], 1.f);
    }
}

// ---------------- batched node post: 32 nodes / block ------------------------
__global__ __launch_bounds__(256, 2) void k_node_post(
    fp h, fp x, const short* __restrict__ wb,
    fp n1B, fp n2B, fp lng, fp lnb,
    const float* __restrict__ agg, const float* __restrict__ cntc,
    const float* __restrict__ xacc, const float* __restrict__ cntr,
    float* __restrict__ outh, float* __restrict__ outx) {
    __shared__ __attribute__((aligned(16))) short nA[32 * 264];   // [h|aggm]
    __shared__ __attribute__((aligned(16))) short nMid[32 * 136];
    __shared__ float nY[32][128];
    __shared__ float nred8[32][8];
    __shared__ float nmu[32], nrs[32];

    const int tid = threadIdx.x;
    const int wave = tid >> 6, mt = wave & 1, nh = wave >> 1;
    const int lane = tid & 63;
    const int nb0 = blockIdx.x * 32;
    const short* n1Wb = wb + 116736;
    const short* n2Wb = wb + 149504;

    for (int p = tid; p < 32 * 128; p += 256) {
        int i = p >> 7, f = p & 127;
        int n = nb0 + i;
        nA[i * 264 + f] = F2B(h[n * 128 + f]);
        float cc = cntc[n]; if (cc < 1.f) cc = 1.f;
        nA[i * 264 + 128 + f] = F2B(agg[n * 128 + f] / cc);
    }
    __syncthreads();

    f32x4 acc[4];
    gemm_tiles(nA, 264, n1Wb, 256, mt, nh * 4, 4, acc);
#pragma unroll
    for (int t = 0; t < 4; t++)
#pragma unroll
        for (int i = 0; i < 4; i++) {
            int m = mt * 16 + (lane >> 4) * 4 + i, n = (nh * 4 + t) * 16 + (lane & 15);
            nMid[m * 136 + n] = F2B(siluf(acc[t][i] + n1B[n]));
        }
    __syncthreads();

    gemm_tiles(nMid, 136, n2Wb, 128, mt, nh * 4, 4, acc);
#pragma unroll
    for (int t = 0; t < 4; t++)
#pragma unroll
        for (int i = 0; i < 4; i++) {
            int m = mt * 16 + (lane >> 4) * 4 + i, n = (nh * 4 + t) * 16 + (lane & 15);
            nY[m][n] = acc[t][i] + n2B[n] + h[(nb0 + m) * 128 + n];
        }
    __syncthreads();

    // LayerNorm
    {
        int i = tid >> 3, j = tid & 7;
        float s = 0.f;
        for (int f = j * 16; f < j * 16 + 16; f++) s += nY[i][f];
        nred8[i][j] = s;
    }
    __syncthreads();
    if (tid < 32) {
        float s = 0.f;
#pragma unroll
        for (int j = 0; j < 8; j++) s += nred8[tid][j];
        nmu[tid] = s * (1.f / 128.f);
    }
    __syncthreads();
    {
        int i = tid >> 3, j = tid & 7;
        float mu = nmu[i], s = 0.f;
        for (int f = j * 16; f < j * 16 + 16; f++) { float d = nY[i][f] - mu; s += d * d; }
        nred8[i][j] = s;
    }
    __syncthreads();
    if (tid < 32) {
        float s = 0.f;
#pragma unroll
        for (int j = 0; j < 8; j++) s += nred8[tid][j];
        nrs[tid] = rsqrtf(s * (1.f / 128.f) + 1e-5f);
    }
    __syncthreads();
    for (int p = tid; p < 32 * 128; p += 256) {
        int i = p >> 7, f = p & 127;
        outh[(nb0 + i) * 128 + f] = (nY[i][f] - nmu[i]) * nrs[i] * lng[f] + lnb[f];
    }
    for (int p = tid; p < 32 * 42; p += 256) {
        int i = p / 42, q = p - i * 42;
        int n = nb0 + i;
        float cr = cntr[n]; if (cr < 1.f) cr = 1.f;
        outx[n * 42 + q] = x[n * 42 + q] + xacc[n * 42 + q] / cr;
    }
}

extern "C" void kernel_launch(void* const* d_in, const int* in_sizes, int n_in,
                              void* d_out, int out_size, void* d_ws, size_t ws_size,
                              hipStream_t stream) {
    fp h   = (fp)d_in[0];
    fp x   = (fp)d_in[1];
    const int* row = (const int*)d_in[2];
    const int* col = (const int*)d_in[3];
    fp attr= (fp)d_in[4];
    fp cw  = (fp)d_in[5];
    fp rW  = (fp)d_in[6];  fp rB  = (fp)d_in[7];
    fp e1W = (fp)d_in[8];  fp e1B = (fp)d_in[9];
    fp e2W = (fp)d_in[10]; fp e2B = (fp)d_in[11];
    fp aW  = (fp)d_in[12]; fp aB  = (fp)d_in[13];
    fp c1W = (fp)d_in[14]; fp c1B = (fp)d_in[15];
    fp c2W = (fp)d_in[16]; fp c2B = (fp)d_in[17];
    fp n1W = (fp)d_in[18]; fp n1B = (fp)d_in[19];
    fp n2W = (fp)d_in[20]; fp n2B = (fp)d_in[21];
    fp lng = (fp)d_in[22]; fp lnb = (fp)d_in[23];

    // fp32 workspace: xacc[840000] agg[2560000] cntr[20000] cntc[20000]
    //                 csum[20000] pool[60000]  -> 3,520,000 floats
    // then bf16 weights: 165,888 shorts
    float* ws   = (float*)d_ws;
    float* xacc = ws;
    float* agg  = ws + 840000;
    float* cntr = ws + 3400000;
    float* cntc = ws + 3420000;
    float* csum = ws + 3440000;
    float* pool = ws + 3460000;
    short* wb   = (short*)(ws + 3520000);

    hipMemsetAsync(d_ws, 0, 3440000 * sizeof(float), stream);

    k_prep_w<<<(165888 + 255) / 256, 256, 0, stream>>>(rW, e1W, e2W, c1W, c2W, n1W, n2W, wb);
    k_node_pre<<<(NN + 255) / 256, 256, 0, stream>>>(x, cw, csum, pool);

    k_edge<<<NE / 32, 256, 0, stream>>>(h, x, row, col, attr, cw, wb,
                                        rB, e1B, e2B, aW, aB, c1B, c2B,
                                        csum, pool, xacc, agg, cntr, cntc);

    float* outh = (float*)d_out;
    float* outx = outh + NN * 128;
    k_node_post<<<NN / 32, 256, 0, stream>>>(h, x, wb, n1B, n2B, lng, lnb,
                                             agg, cntc, xacc, cntr, outh, outx);
}

// Round 5
// 1160.729 us; speedup vs baseline: 16.5039x; 1.3510x over previous
//
#include <hip/hip_runtime.h>
#include <math.h>

#define NN 20000
#define NE 320000

typedef const float* fp;
typedef short short8 __attribute__((ext_vector_type(8)));
typedef float f32x4 __attribute__((ext_vector_type(4)));

__device__ __forceinline__ short F2B(float f) {
    unsigned u = __float_as_uint(f);
    return (short)((u + 0x7fffu + ((u >> 16) & 1u)) >> 16);
}
__device__ __forceinline__ float B2F(short s) {
    return __uint_as_float(((unsigned)(unsigned short)s) << 16);
}
__device__ __forceinline__ float siluf(float v) { return v / (1.f + __expf(-v)); }

// ---------------- weight fp32->bf16 (layout in shorts): ---------------------
// 0:      e1hh [128][256]  (e1W cols 0..255: hr|hc)
// 32768:  Wc   [128][256]  (folded radial: e1W[:,256:384] @ rW)  [k_fold]
// 65536:  e2W  [128][128]
// 81920:  c1W  [128][128]
// 98304:  c2W  [16][128] (rows 14,15 zero)
// 100352: n1W  [128][256]
// 133120: n2W  [128][128]   end 149504
__global__ void k_prep_w(fp e1W, fp e2W, fp c1W, fp c2W, fp n1W, fp n2W,
                         short* __restrict__ wb) {
    int i = blockIdx.x * 256 + threadIdx.x;
    if (i >= 149504) return;
    if (i >= 32768 && i < 65536) return;  // Wc filled by k_fold
    float v;
    if (i < 32768)       { int o = i >> 8, k = i & 255; v = e1W[o * 384 + k]; }
    else if (i < 81920)  v = e2W[i - 65536];
    else if (i < 98304)  v = c1W[i - 81920];
    else if (i < 100352) { int q = i - 98304; v = (q < 1792) ? c2W[q] : 0.f; }
    else if (i < 133120) v = n1W[i - 100352];
    else                 v = n2W[i - 133120];
    wb[i] = F2B(v);
}

// Wc[o][k] = sum_m e1W[o][256+m] * rW[m][k];  bc[o] = sum_m e1W[o][256+m] * rB[m]
__global__ void k_fold(fp e1W, fp rW, fp rB, short* __restrict__ wb,
                       float* __restrict__ bc) {
    int o = blockIdx.x, k = threadIdx.x;  // 128 blocks x 256 threads
    float acc = 0.f;
    for (int m = 0; m < 128; m++) acc += e1W[o * 384 + 256 + m] * rW[m * 256 + k];
    wb[32768 + o * 256 + k] = F2B(acc);
    if (k == 0) {
        float b = 0.f;
        for (int m = 0; m < 128; m++) b += e1W[o * 384 + 256 + m] * rB[m];
        bc[o] = b;
    }
}

__global__ void k_prep_h(fp h, short* __restrict__ hb) {
    int i = blockIdx.x * 256 + threadIdx.x;
    if (i < NN * 128) hb[i] = F2B(h[i]);
}

__global__ void k_node_pre(fp x, fp cw, float* __restrict__ csum, float* __restrict__ pool) {
    int n = blockIdx.x * blockDim.x + threadIdx.x;
    if (n >= NN) return;
    float cnt = 0.f, px = 0.f, py = 0.f, pz = 0.f;
#pragma unroll
    for (int c = 0; c < 14; c++) {
        float w = cw[n * 14 + c];
        if (w != 0.f) {
            cnt += 1.f;
            px += x[(n * 14 + c) * 3 + 0];
            py += x[(n * 14 + c) * 3 + 1];
            pz += x[(n * 14 + c) * 3 + 2];
        }
    }
    if (cnt < 1.f) cnt = 1.f;
    csum[n] = cnt;
    pool[n * 3 + 0] = px / cnt;
    pool[n * 3 + 1] = py / cnt;
    pool[n * 3 + 2] = pz / cnt;
}

// accumulate O += A(LDS/any, stride sA shorts) @ W(stride Ws)^T ; no zeroing
__device__ __forceinline__ void gemm_lds(const short* __restrict__ A, int sA,
                                         const short* __restrict__ W, int Ws, int K,
                                         int mt, int nt0, int nts, f32x4* acc) {
    const int lane = threadIdx.x & 63;
    const short* ap = A + (mt * 16 + (lane & 15)) * sA + ((lane >> 4) * 8);
    for (int k0 = 0; k0 < K; k0 += 32) {
        short8 a = *(const short8*)(ap + k0);
#pragma unroll
        for (int t = 0; t < nts; t++) {
            short8 b = *(const short8*)(W + ((nt0 + t) * 16 + (lane & 15)) * Ws + k0 + ((lane >> 4) * 8));
            acc[t] = __builtin_amdgcn_mfma_f32_16x16x32_bf16(a, b, acc[t], 0, 0, 0);
        }
    }
}
// same but A rows come from global table rows (per-row base pointers)
__device__ __forceinline__ void gemm_grow(const short* __restrict__ arow,
                                          const short* __restrict__ W, int Ws, int K,
                                          int nt0, int nts, f32x4* acc) {
    const int lane = threadIdx.x & 63;
    for (int k0 = 0; k0 < K; k0 += 32) {
        short8 a = *(const short8*)(arow + k0);
#pragma unroll
        for (int t = 0; t < nts; t++) {
            short8 b = *(const short8*)(W + ((nt0 + t) * 16 + (lane & 15)) * Ws + k0 + ((lane >> 4) * 8));
            acc[t] = __builtin_amdgcn_mfma_f32_16x16x32_bf16(a, b, acc[t], 0, 0, 0);
        }
    }
}

// ---------------- fused edge kernel: 32 edges / block, 256 threads -----------
__global__ __launch_bounds__(256, 3) void k_edge(
    fp x, const int* __restrict__ row, const int* __restrict__ col,
    fp attr, fp cw, const short* __restrict__ hb, const short* __restrict__ wb,
    fp e1B, fp e2B, fp aW, fp aB, fp c1B, fp c2B,
    const float* __restrict__ bc, const float* __restrict__ csum,
    const float* __restrict__ poolc,
    float* __restrict__ xacc, float* __restrict__ agg,
    float* __restrict__ cntr, float* __restrict__ cntc) {
    // R1 (shorts): radq[32*264] in [0,8448) during prep+e1;
    // then v1 [0,4352) | v2 [4352,8704) | c1o [8704,13056)
    __shared__ __attribute__((aligned(16))) short R1[13056];
    __shared__ float s_xr2[32 * 42];
    __shared__ float T[4][352];  // per-wave: xc[0,42) cwr[42,56) cwc[56,70) tmp2w[72,344) stride17
    __shared__ int   s_r[32], s_c[32];
    __shared__ float s_inv[32];
    __shared__ float s_ch[32][14], s_pool[32][14];
    __shared__ float s_red8[32][8];
    __shared__ float s_gate[32];

    const int tid = threadIdx.x, lane = tid & 63, w = tid >> 6;
    const int bb = lane & 15, quad = lane >> 4;

    if (tid < 32) { s_r[tid] = row[blockIdx.x * 32 + tid]; s_c[tid] = col[blockIdx.x * 32 + tid]; }
    __syncthreads();

    // ======== prep: wave w handles edges w*8 .. w*8+7, one at a time ========
    float* slot = T[w];
    float* t2w = slot + 72;
    for (int i8 = 0; i8 < 8; i8++) {
        const int e = w * 8 + i8;
        const int r = s_r[e], cl = s_c[e];
        if (lane < 42) {
            s_xr2[e * 42 + lane] = x[(size_t)r * 42 + lane];
            slot[lane] = x[(size_t)cl * 42 + lane];
        }
        if (lane < 14)      slot[42 + lane] = cw[r * 14 + lane];
        else if (lane < 28) slot[56 + (lane - 14)] = cw[cl * 14 + (lane - 14)];
        __builtin_amdgcn_wave_barrier();

        // MFMA1: tmp2 = msg @ ac   (A: m=i=lane&15, k=j=quad*8+t; B: n=b=lane&15)
        const int ii = bb;
        const int iic = ii < 14 ? ii : 13;
        float xr0 = s_xr2[e * 42 + iic * 3], xr1 = s_xr2[e * 42 + iic * 3 + 1],
              xr2v = s_xr2[e * 42 + iic * 3 + 2];
        float cwri = slot[42 + iic];
        short8 msgv, acv;
#pragma unroll
        for (int t = 0; t < 8; t++) {
            int jj = quad * 8 + t, jc = jj < 14 ? jj : 13;
            float dx = xr0 - slot[jc * 3], dy = xr1 - slot[jc * 3 + 1], dz = xr2v - slot[jc * 3 + 2];
            float m = sqrtf(dx * dx + dy * dy + dz * dz) * cwri * slot[56 + jc];
            msgv[t] = (ii < 14 && jj < 14) ? F2B(m) : (short)0;
            acv[t] = F2B(attr[(size_t)cl * 224 + jc * 16 + bb]);
        }
        f32x4 t2 = (f32x4){0.f, 0.f, 0.f, 0.f};
        t2 = __builtin_amdgcn_mfma_f32_16x16x32_bf16(msgv, acv, t2, 0, 0, 0);
#pragma unroll
        for (int g = 0; g < 4; g++) t2w[(quad * 4 + g) * 17 + bb] = t2[g];
        __builtin_amdgcn_wave_barrier();

        // MFMA2: rad = ar^T @ tmp2  (A: m=a=lane&15, k=i=quad*8+t, zero for i>=14)
        short8 arv, t2v;
#pragma unroll
        for (int t = 0; t < 8; t++) {
            int kk = quad * 8 + t, kc = kk < 16 ? kk : 15;
            t2v[t] = F2B(t2w[kc * 17 + bb]);
            arv[t] = (kk < 14) ? F2B(attr[(size_t)r * 224 + kk * 16 + bb]) : (short)0;
        }
        f32x4 rad = (f32x4){0.f, 0.f, 0.f, 0.f};
        rad = __builtin_amdgcn_mfma_f32_16x16x32_bf16(arv, t2v, rad, 0, 0, 0);

        float ss = rad[0] * rad[0] + rad[1] * rad[1] + rad[2] * rad[2] + rad[3] * rad[3];
#pragma unroll
        for (int off = 32; off > 0; off >>= 1) ss += __shfl_xor(ss, off, 64);
        float inv = 1.f / (sqrtf(ss) + 1.f);
        if (lane == 0) s_inv[e] = inv;
#pragma unroll
        for (int g = 0; g < 4; g++)
            R1[e * 264 + (quad * 4 + g) * 16 + bb] = F2B(rad[g] * inv);
        __builtin_amdgcn_wave_barrier();
    }
    __syncthreads();

    // ======== GEMM chain: wave tile mt=w&1 (rows), nh=w>>1 (cols) ========
    const int mt = w & 1, nh = w >> 1;
    const int m_ = mt * 16 + bb;  // A-load row (edge idx in block)
    f32x4 acc[4];
#pragma unroll
    for (int t = 0; t < 4; t++) acc[t] = (f32x4){0.f, 0.f, 0.f, 0.f};

    // e1 = silu(hr@W1 + hc@W2 + radq@Wc + e1B + bc*inv)
    {
        const short* ar_ = hb + (size_t)s_r[m_] * 128 + quad * 8;
        const short* ac_ = hb + (size_t)s_c[m_] * 128 + quad * 8;
        gemm_grow(ar_, wb, 256, 128, nh * 4, 4, acc);          // hr chunk (W cols 0..127)
        gemm_grow(ac_, wb + 128, 256, 128, nh * 4, 4, acc);    // hc chunk (W cols 128..255)
        gemm_lds(R1, 264, wb + 32768, 256, 256, mt, nh * 4, 4, acc);  // radq chunk
    }
    __syncthreads();
    short* V1 = R1;
    short* V2 = R1 + 4352;
    short* C1O = R1 + 8704;
#pragma unroll
    for (int t = 0; t < 4; t++)
#pragma unroll
        for (int i = 0; i < 4; i++) {
            int m = mt * 16 + quad * 4 + i, n = (nh * 4 + t) * 16 + bb;
            V1[m * 136 + n] = F2B(siluf(acc[t][i] + e1B[n] + bc[n] * s_inv[m]));
        }
    __syncthreads();

    // e2
#pragma unroll
    for (int t = 0; t < 4; t++) acc[t] = (f32x4){0.f, 0.f, 0.f, 0.f};
    gemm_lds(V1, 136, wb + 65536, 128, 128, mt, nh * 4, 4, acc);
    __syncthreads();
#pragma unroll
    for (int t = 0; t < 4; t++)
#pragma unroll
        for (int i = 0; i < 4; i++) {
            int m = mt * 16 + quad * 4 + i, n = (nh * 4 + t) * 16 + bb;
            V2[m * 136 + n] = F2B(siluf(acc[t][i] + e2B[n]));
        }
    __syncthreads();

    // attention gate
    {
        int e = tid >> 3, j = tid & 7;
        float s = 0.f;
        for (int f = j * 16; f < j * 16 + 16; f++) s += B2F(V2[e * 136 + f]) * aW[f];
        s_red8[e][j] = s;
    }
    __syncthreads();
    if (tid < 32) {
        float s = 0.f;
#pragma unroll
        for (int j = 0; j < 8; j++) s += s_red8[tid][j];
        s_gate[tid] = 1.f / (1.f + __expf(-(s + aB[0])));
    }
    __syncthreads();
    for (int p = tid; p < 32 * 128; p += 256) {
        int e = p >> 7, f = p & 127;
        V1[e * 136 + f] = F2B(B2F(V2[e * 136 + f]) * s_gate[e]);  // v3 over v1
    }
    __syncthreads();

    // c1
#pragma unroll
    for (int t = 0; t < 4; t++) acc[t] = (f32x4){0.f, 0.f, 0.f, 0.f};
    gemm_lds(V1, 136, wb + 81920, 128, 128, mt, nh * 4, 4, acc);
    __syncthreads();
#pragma unroll
    for (int t = 0; t < 4; t++)
#pragma unroll
        for (int i = 0; i < 4; i++) {
            int m = mt * 16 + quad * 4 + i, n = (nh * 4 + t) * 16 + bb;
            C1O[m * 136 + n] = F2B(siluf(acc[t][i] + c1B[n]));
        }
    __syncthreads();

    // c2 (14 outputs; nh==0 waves only)
    if (nh == 0) {
        f32x4 a4 = (f32x4){0.f, 0.f, 0.f, 0.f};
        gemm_lds(C1O, 136, wb + 98304, 128, 128, mt, 0, 1, &a4);
#pragma unroll
        for (int i = 0; i < 4; i++) {
            int m = mt * 16 + quad * 4 + i;
            if (bb < 14) s_ch[m][bb] = a4[i] + c2B[bb];
        }
    }
    __syncthreads();

    // roller pooling
    if (tid < 32) {
        int t = (int)(csum[s_r[tid]] + 0.5f) - 1;
        if (t < 0) t = 0; if (t > 13) t = 13;
        int Wd = 14 - t;
        for (int i = 0; i < 14; i++) {
            int jend = i + Wd - 1; if (jend > 13) jend = 13;
            float a = 0.f;
            for (int j = i; j <= jend; j++) a += s_ch[tid][j];
            s_pool[tid][i] = a / (float)Wd;
        }
    }
    __syncthreads();

    // scatters
    for (int p = tid; p < 32 * 42; p += 256) {
        int e = p / 42, q = p - e * 42, i = q / 3, d = q - i * 3;
        float diff = s_xr2[e * 42 + q] - poolc[s_c[e] * 3 + d];
        atomicAdd(&xacc[(size_t)s_r[e] * 42 + q], diff * s_pool[e][i]);
    }
    for (int p = tid; p < 32 * 128; p += 256) {
        int e = p >> 7, f = p & 127;
        atomicAdd(&agg[(size_t)s_c[e] * 128 + f], B2F(V1[e * 136 + f]));
    }
    if (tid < 32) {
        atomicAdd(&cntr[s_r[tid]], 1.f);
        atomicAdd(&cntc[s_c[tid]], 1.f);
    }
}

// ---------------- batched node post: 32 nodes / block ------------------------
__global__ __launch_bounds__(256, 2) void k_node_post(
    fp h, fp x, const short* __restrict__ wb,
    fp n1B, fp n2B, fp lng, fp lnb,
    const float* __restrict__ agg, const float* __restrict__ cntc,
    const float* __restrict__ xacc, const float* __restrict__ cntr,
    float* __restrict__ outh, float* __restrict__ outx) {
    __shared__ __attribute__((aligned(16))) short nA[32 * 264];
    __shared__ __attribute__((aligned(16))) short nMid[32 * 136];
    __shared__ float nY[32][128];
    __shared__ float nred8[32][8];
    __shared__ float nmu[32], nrs[32];

    const int tid = threadIdx.x;
    const int wave = tid >> 6, mt = wave & 1, nh = wave >> 1;
    const int lane = tid & 63, bb = lane & 15, quad = lane >> 4;
    const int nb0 = blockIdx.x * 32;
    const short* n1Wb = wb + 100352;
    const short* n2Wb = wb + 133120;

    for (int p = tid; p < 32 * 128; p += 256) {
        int i = p >> 7, f = p & 127;
        int n = nb0 + i;
        nA[i * 264 + f] = F2B(h[(size_t)n * 128 + f]);
        float cc = cntc[n]; if (cc < 1.f) cc = 1.f;
        nA[i * 264 + 128 + f] = F2B(agg[(size_t)n * 128 + f] / cc);
    }
    __syncthreads();

    f32x4 acc[4];
#pragma unroll
    for (int t = 0; t < 4; t++) acc[t] = (f32x4){0.f, 0.f, 0.f, 0.f};
    gemm_lds(nA, 264, n1Wb, 256, 256, mt, nh * 4, 4, acc);
#pragma unroll
    for (int t = 0; t < 4; t++)
#pragma unroll
        for (int i = 0; i < 4; i++) {
            int m = mt * 16 + quad * 4 + i, n = (nh * 4 + t) * 16 + bb;
            nMid[m * 136 + n] = F2B(siluf(acc[t][i] + n1B[n]));
        }
    __syncthreads();

#pragma unroll
    for (int t = 0; t < 4; t++) acc[t] = (f32x4){0.f, 0.f, 0.f, 0.f};
    gemm_lds(nMid, 136, n2Wb, 128, 128, mt, nh * 4, 4, acc);
#pragma unroll
    for (int t = 0; t < 4; t++)
#pragma unroll
        for (int i = 0; i < 4; i++) {
            int m = mt * 16 + quad * 4 + i, n = (nh * 4 + t) * 16 + bb;
            nY[m][n] = acc[t][i] + n2B[n] + h[(size_t)(nb0 + m) * 128 + n];
        }
    __syncthreads();

    {
        int i = tid >> 3, j = tid & 7;
        float s = 0.f;
        for (int f = j * 16; f < j * 16 + 16; f++) s += nY[i][f];
        nred8[i][j] = s;
    }
    __syncthreads();
    if (tid < 32) {
        float s = 0.f;
#pragma unroll
        for (int j = 0; j < 8; j++) s += nred8[tid][j];
        nmu[tid] = s * (1.f / 128.f);
    }
    __syncthreads();
    {
        int i = tid >> 3, j = tid & 7;
        float mu = nmu[i], s = 0.f;
        for (int f = j * 16; f < j * 16 + 16; f++) { float d = nY[i][f] - mu; s += d * d; }
        nred8[i][j] = s;
    }
    __syncthreads();
    if (tid < 32) {
        float s = 0.f;
#pragma unroll
        for (int j = 0; j < 8; j++) s += nred8[tid][j];
        nrs[tid] = rsqrtf(s * (1.f / 128.f) + 1e-5f);
    }
    __syncthreads();
    for (int p = tid; p < 32 * 128; p += 256) {
        int i = p >> 7, f = p & 127;
        outh[(size_t)(nb0 + i) * 128 + f] = (nY[i][f] - nmu[i]) * nrs[i] * lng[f] + lnb[f];
    }
    for (int p = tid; p < 32 * 42; p += 256) {
        int i = p / 42, q = p - i * 42;
        int n = nb0 + i;
        float cr = cntr[n]; if (cr < 1.f) cr = 1.f;
        outx[(size_t)n * 42 + q] = x[(size_t)n * 42 + q] + xacc[(size_t)n * 42 + q] / cr;
    }
}

extern "C" void kernel_launch(void* const* d_in, const int* in_sizes, int n_in,
                              void* d_out, int out_size, void* d_ws, size_t ws_size,
                              hipStream_t stream) {
    fp h   = (fp)d_in[0];
    fp x   = (fp)d_in[1];
    const int* row = (const int*)d_in[2];
    const int* col = (const int*)d_in[3];
    fp attr= (fp)d_in[4];
    fp cw  = (fp)d_in[5];
    fp rW  = (fp)d_in[6];  fp rB  = (fp)d_in[7];
    fp e1W = (fp)d_in[8];  fp e1B = (fp)d_in[9];
    fp e2W = (fp)d_in[10]; fp e2B = (fp)d_in[11];
    fp aW  = (fp)d_in[12]; fp aB  = (fp)d_in[13];
    fp c1W = (fp)d_in[14]; fp c1B = (fp)d_in[15];
    fp c2W = (fp)d_in[16]; fp c2B = (fp)d_in[17];
    fp n1W = (fp)d_in[18]; fp n1B = (fp)d_in[19];
    fp n2W = (fp)d_in[20]; fp n2B = (fp)d_in[21];
    fp lng = (fp)d_in[22]; fp lnb = (fp)d_in[23];

    // fp32 ws: xacc[0,840000) agg[840000,3400000) cntr cntc csum[3440000) pool[3460000)
    // bc @3520000 (128); hb (shorts) @f32-off 3520128 (1,280,000 f32);
    // wb (shorts) @f32-off 4800128 (74,752 f32) -> total 4,874,880 f32 = 19.5 MB
    float* ws   = (float*)d_ws;
    float* xacc = ws;
    float* agg  = ws + 840000;
    float* cntr = ws + 3400000;
    float* cntc = ws + 3420000;
    float* csum = ws + 3440000;
    float* pool = ws + 3460000;
    float* bc   = ws + 3520000;
    short* hb   = (short*)(ws + 3520128);
    short* wb   = (short*)(ws + 4800128);

    hipMemsetAsync(d_ws, 0, 3440000 * sizeof(float), stream);

    k_prep_w<<<(149504 + 255) / 256, 256, 0, stream>>>(e1W, e2W, c1W, c2W, n1W, n2W, wb);
    k_fold<<<128, 256, 0, stream>>>(e1W, rW, rB, wb, bc);
    k_prep_h<<<(NN * 128 + 255) / 256, 256, 0, stream>>>(h, hb);
    k_node_pre<<<(NN + 255) / 256, 256, 0, stream>>>(x, cw, csum, pool);

    k_edge<<<NE / 32, 256, 0, stream>>>(x, row, col, attr, cw, hb, wb,
                                        e1B, e2B, aW, aB, c1B, c2B,
                                        bc, csum, pool, xacc, agg, cntr, cntc);

    float* outh = (float*)d_out;
    float* outx = outh + NN * 128;
    k_node_post<<<NN / 32, 256, 0, stream>>>(h, x, wb, n1B, n2B, lng, lnb,
                                             agg, cntc, xacc, cntr, outh, outx);
}